// Round 7
// baseline (133.134 us; speedup 1.0000x reference)
//
#include <hip/hip_runtime.h>
#include <hip/hip_bf16.h>
#include <stdint.h>

#define BATCH 256
#define TSLOT 27
#define NTOT  (BATCH * TSLOT)   // 6912
#define DIM   1024
#define NS64  108               // max 64-row strips (NTOT/64)
#define NTRI64 (NS64 * (NS64 + 1) / 2)  // 5886 wave-tiles (upper bound)

typedef __attribute__((ext_vector_type(8))) short short8;
typedef __attribute__((ext_vector_type(4))) float f32x4;

// ---------- prep + scan: offsets, meta, clab tail, accum zero ----------
__global__ __launch_bounds__(256) void prepscan_kernel(const int* __restrict__ tgt,
                                                       int* __restrict__ offs,
                                                       int* __restrict__ meta,
                                                       int* __restrict__ clab,
                                                       float* __restrict__ accum) {
    int b = threadIdx.x;
    const int* t = tgt + b * TSLOT;
    int fz = 1;
    for (int i = 1; i < TSLOT; ++i) {
        if (t[i] == 0) { fz = i; break; }
    }
    __shared__ int sh[256];
    sh[b] = fz;
    __syncthreads();
    for (int d = 1; d < 256; d <<= 1) {
        int v = (b >= d) ? sh[b - d] : 0;
        __syncthreads();
        sh[b] += v;
        __syncthreads();
    }
    offs[b] = sh[b] - fz;  // exclusive
    if (b < 2) accum[b] = 0.0f;
    __syncthreads();
    int nv = sh[255];
    int npad = ((nv + 63) / 64) * 64;   // 64-granular padding now
    if (b == 255) {
        offs[256] = nv;
        meta[0] = nv;
        meta[1] = npad;
    }
    if (b < npad - nv) clab[nv + b] = -1;  // <= 63 entries
}

// ---------- wave-per-row L2-normalize f32 -> bf16, scatter compacted ----------
__global__ __launch_bounds__(256) void norm_c_kernel(const float* __restrict__ in,
                                                     const int* __restrict__ tgt,
                                                     const int* __restrict__ offs,
                                                     __hip_bfloat16* __restrict__ cfb,
                                                     int* __restrict__ clab) {
    const int wv   = blockIdx.x * 4 + (threadIdx.x >> 6);
    const int lane = threadIdx.x & 63;
    const int b = wv / TSLOT, t = wv - b * TSLOT;
    const int o0 = offs[b], o1 = offs[b + 1];
    if (t >= o1 - o0) return;
    const int dest = o0 + t;
    const float* src = in + (size_t)wv * DIM + lane * 16;
    float4 v0 = *(const float4*)(src);
    float4 v1 = *(const float4*)(src + 4);
    float4 v2 = *(const float4*)(src + 8);
    float4 v3 = *(const float4*)(src + 12);
    float ss = v0.x*v0.x + v0.y*v0.y + v0.z*v0.z + v0.w*v0.w
             + v1.x*v1.x + v1.y*v1.y + v1.z*v1.z + v1.w*v1.w
             + v2.x*v2.x + v2.y*v2.y + v2.z*v2.z + v2.w*v2.w
             + v3.x*v3.x + v3.y*v3.y + v3.z*v3.z + v3.w*v3.w;
    #pragma unroll
    for (int off = 1; off < 64; off <<= 1) ss += __shfl_xor(ss, off);
    const float scale = 1.0f / fmaxf(sqrtf(ss), 1e-12f);
    unsigned short h[16];
    float f[16] = {v0.x,v0.y,v0.z,v0.w, v1.x,v1.y,v1.z,v1.w,
                   v2.x,v2.y,v2.z,v2.w, v3.x,v3.y,v3.z,v3.w};
    #pragma unroll
    for (int j = 0; j < 16; ++j) {
        __hip_bfloat16 hv = __float2bfloat16(f[j] * scale);
        h[j] = *(unsigned short*)&hv;
    }
    unsigned short* dst = (unsigned short*)cfb + (size_t)dest * DIM + lane * 16;
    *(ushort4*)(dst)      = *(ushort4*)&h[0];
    *(ushort4*)(dst + 4)  = *(ushort4*)&h[4];
    *(ushort4*)(dst + 8)  = *(ushort4*)&h[8];
    *(ushort4*)(dst + 12) = *(ushort4*)&h[12];
    if (lane == 0) clab[dest] = tgt[wv];
}

// ---------- barrier-free direct-fragment GEMM: 1 wave per 64x64 tile ----------
// No LDS, no barriers. MFMA A/B fragments loaded straight from global:
// frag addr = base(row) + s*64 + (lane>>4)*16; all 32 K-step offsets fit the
// 13-bit immediate, so the unrolled loop has zero per-step address math.
#define LOAD4(dst, p0, p1, p2, p3, S)                         \
    dst##0 = *(const short8*)((p0) + (S) * 64);               \
    dst##1 = *(const short8*)((p1) + (S) * 64);               \
    dst##2 = *(const short8*)((p2) + (S) * 64);               \
    dst##3 = *(const short8*)((p3) + (S) * 64);

#define MM16(A, B)                                                             \
    acc[0][0] = __builtin_amdgcn_mfma_f32_16x16x32_bf16(A##0, B##0, acc[0][0], 0, 0, 0); \
    acc[0][1] = __builtin_amdgcn_mfma_f32_16x16x32_bf16(A##0, B##1, acc[0][1], 0, 0, 0); \
    acc[0][2] = __builtin_amdgcn_mfma_f32_16x16x32_bf16(A##0, B##2, acc[0][2], 0, 0, 0); \
    acc[0][3] = __builtin_amdgcn_mfma_f32_16x16x32_bf16(A##0, B##3, acc[0][3], 0, 0, 0); \
    acc[1][0] = __builtin_amdgcn_mfma_f32_16x16x32_bf16(A##1, B##0, acc[1][0], 0, 0, 0); \
    acc[1][1] = __builtin_amdgcn_mfma_f32_16x16x32_bf16(A##1, B##1, acc[1][1], 0, 0, 0); \
    acc[1][2] = __builtin_amdgcn_mfma_f32_16x16x32_bf16(A##1, B##2, acc[1][2], 0, 0, 0); \
    acc[1][3] = __builtin_amdgcn_mfma_f32_16x16x32_bf16(A##1, B##3, acc[1][3], 0, 0, 0); \
    acc[2][0] = __builtin_amdgcn_mfma_f32_16x16x32_bf16(A##2, B##0, acc[2][0], 0, 0, 0); \
    acc[2][1] = __builtin_amdgcn_mfma_f32_16x16x32_bf16(A##2, B##1, acc[2][1], 0, 0, 0); \
    acc[2][2] = __builtin_amdgcn_mfma_f32_16x16x32_bf16(A##2, B##2, acc[2][2], 0, 0, 0); \
    acc[2][3] = __builtin_amdgcn_mfma_f32_16x16x32_bf16(A##2, B##3, acc[2][3], 0, 0, 0); \
    acc[3][0] = __builtin_amdgcn_mfma_f32_16x16x32_bf16(A##3, B##0, acc[3][0], 0, 0, 0); \
    acc[3][1] = __builtin_amdgcn_mfma_f32_16x16x32_bf16(A##3, B##1, acc[3][1], 0, 0, 0); \
    acc[3][2] = __builtin_amdgcn_mfma_f32_16x16x32_bf16(A##3, B##2, acc[3][2], 0, 0, 0); \
    acc[3][3] = __builtin_amdgcn_mfma_f32_16x16x32_bf16(A##3, B##3, acc[3][3], 0, 0, 0);

__global__ __launch_bounds__(64, 3) void gemm_kernel(const __hip_bfloat16* __restrict__ fb,
                                                     const int* __restrict__ clab,
                                                     const int* __restrict__ meta,
                                                     float* __restrict__ Ppos,
                                                     float* __restrict__ Pneg) {
    int t = blockIdx.x;
    int bi = 0;
    while (t >= NS64 - bi) { t -= NS64 - bi; ++bi; }
    const int bj = bi + t;
    const int npad = meta[1];
    const int c0 = bj * 64;
    if (c0 >= npad) return;
    const int r0 = bi * 64;
    const bool diag = (bi == bj);

    const int lane = threadIdx.x;
    const int rsel = lane & 15, tsl = lane >> 4;

    const char* fbyte = (const char*)fb;
    const char* pa0 = fbyte + (size_t)(r0 + rsel) * 2048      + tsl * 16;
    const char* pa1 = pa0 + 16 * 2048;
    const char* pa2 = pa0 + 32 * 2048;
    const char* pa3 = pa0 + 48 * 2048;
    const char* pb0 = fbyte + (size_t)(c0 + rsel) * 2048      + tsl * 16;
    const char* pb1 = pb0 + 16 * 2048;
    const char* pb2 = pb0 + 32 * 2048;
    const char* pb3 = pb0 + 48 * 2048;

    f32x4 acc[4][4] = {};
    short8 a00, a01, a02, a03, b00, b01, b02, b03;   // buffer 0
    short8 a10, a11, a12, a13, b10, b11, b12, b13;   // buffer 1

    LOAD4(a0, pa0, pa1, pa2, pa3, 0)
    LOAD4(b0, pb0, pb1, pb2, pb3, 0)
    #pragma unroll
    for (int ss = 0; ss < 16; ++ss) {
        const int s = 2 * ss;
        if (s + 1 < 32) {
            LOAD4(a1, pa0, pa1, pa2, pa3, s + 1)
            LOAD4(b1, pb0, pb1, pb2, pb3, s + 1)
        }
        MM16(a0, b0)
        if (s + 2 < 32) {
            LOAD4(a0, pa0, pa1, pa2, pa3, s + 2)
            LOAD4(b0, pb0, pb1, pb2, pb3, s + 2)
        }
        MM16(a1, b1)
    }

    // ---- epilogue: masked exp + shfl reductions, disjoint partial stores ----
    // C/D layout: col = lane&15, row = (lane>>4)*4 + reg
    const int c = rsel, g = tsl;
    float cpos[4] = {0, 0, 0, 0}, cneg[4] = {0, 0, 0, 0};

    #pragma unroll
    for (int m = 0; m < 4; ++m) {
        #pragma unroll
        for (int rg = 0; rg < 4; ++rg) {
            const int gi = r0 + m * 16 + g * 4 + rg;
            const int li = clab[gi];
            float rp = 0.0f, rn = 0.0f;
            #pragma unroll
            for (int n = 0; n < 4; ++n) {
                const int gj = c0 + n * 16 + c;
                const int lj = clab[gj];
                const float s = acc[m][n][rg];
                if (li >= 0 && lj >= 0) {
                    if (li == lj) { float e = __expf(-s); rp += e; cpos[n] += e; }
                    else          { float e = __expf(s);  rn += e; cneg[n] += e; }
                }
            }
            #pragma unroll
            for (int off = 1; off <= 8; off <<= 1) {
                rp += __shfl_xor(rp, off);
                rn += __shfl_xor(rn, off);
            }
            if (c == 0) {
                Ppos[(size_t)bj * NTOT + gi] = rp;   // slot bj (>= bi)
                Pneg[(size_t)bj * NTOT + gi] = rn;
            }
        }
    }
    if (!diag) {
        #pragma unroll
        for (int n = 0; n < 4; ++n) {
            float p = cpos[n], q = cneg[n];
            p += __shfl_xor(p, 16); p += __shfl_xor(p, 32);
            q += __shfl_xor(q, 16); q += __shfl_xor(q, 32);
            if (g == 0) {
                const int gj = c0 + n * 16 + c;
                Ppos[(size_t)bi * NTOT + gj] = p;    // slot bi (< bj)
                Pneg[(size_t)bi * NTOT + gj] = q;
            }
        }
    }
}

// ---------- finalize: coalesced gather, masked mean of log1p(spos*sneg) ----------
__global__ __launch_bounds__(256) void finalize_kernel(const int* __restrict__ clab,
                                                       const int* __restrict__ meta,
                                                       const float* __restrict__ Ppos,
                                                       const float* __restrict__ Pneg,
                                                       float* __restrict__ accum) {
    int i = blockIdx.x * blockDim.x + threadIdx.x;
    const int npad = meta[1];
    const int nta = npad >> 6;
    float s = 0.0f, cnt = 0.0f;
    if (i < npad && clab[i] >= 0) {
        float sp = 0.0f, sn = 0.0f;
        for (int t = 0; t < nta; ++t) {
            sp += Ppos[(size_t)t * NTOT + i];
            sn += Pneg[(size_t)t * NTOT + i];
        }
        s = log1pf(sp * sn);
        cnt = 1.0f;
    }
    #pragma unroll
    for (int off = 1; off < 64; off <<= 1) {
        s   += __shfl_xor(s, off);
        cnt += __shfl_xor(cnt, off);
    }
    __shared__ float sh[8];
    int lane = threadIdx.x & 63, w = threadIdx.x >> 6;
    if (lane == 0) { sh[w] = s; sh[4 + w] = cnt; }
    __syncthreads();
    if (threadIdx.x == 0) {
        atomicAdd(&accum[0], sh[0] + sh[1] + sh[2] + sh[3]);
        atomicAdd(&accum[1], sh[4] + sh[5] + sh[6] + sh[7]);
    }
}

__global__ void writeout_kernel(const float* __restrict__ accum, float* __restrict__ out) {
    out[0] = accum[0] / accum[1];
}

extern "C" void kernel_launch(void* const* d_in, const int* in_sizes, int n_in,
                              void* d_out, int out_size, void* d_ws, size_t ws_size,
                              hipStream_t stream) {
    (void)in_sizes; (void)n_in; (void)out_size; (void)ws_size;
    const float* input_f = (const float*)d_in[0];
    const int*   target  = (const int*)d_in[1];
    float* out = (float*)d_out;

    char* ws = (char*)d_ws;
    const size_t FB_BYTES = (size_t)NTOT * DIM * 2;      // 14,155,776
    __hip_bfloat16* cfb = (__hip_bfloat16*)ws;
    char* p = ws + FB_BYTES;
    int*   clab  = (int*)p;            p += NTOT * 4;
    int*   offs  = (int*)p;            p += 4096;
    int*   meta  = (int*)p;            p += 256;
    float* accum = (float*)p;          p += 256;
    float* Ppos  = (float*)p;          p += (size_t)NS64 * NTOT * 4;  // 2.99 MB
    float* Pneg  = (float*)p;

    prepscan_kernel<<<dim3(1), dim3(256), 0, stream>>>(target, offs, meta, clab, accum);
    norm_c_kernel<<<dim3(NTOT / 4), dim3(256), 0, stream>>>(input_f, target, offs, cfb, clab);
    gemm_kernel<<<dim3(NTRI64), dim3(64), 0, stream>>>(cfb, clab, meta, Ppos, Pneg);
    finalize_kernel<<<dim3((NTOT + 255) / 256), dim3(256), 0, stream>>>(clab, meta, Ppos, Pneg, accum);
    writeout_kernel<<<dim3(1), dim3(1), 0, stream>>>(accum, out);
}

// Round 8
// 69.806 us; speedup vs baseline: 1.9072x; 1.9072x over previous
//
#include <hip/hip_runtime.h>
#include <hip/hip_bf16.h>
#include <stdint.h>

#define BATCH 256
#define TSLOT 27
#define NTOT  (BATCH * TSLOT)   // 6912
#define DIM   1024
#define BM    128
#define NTILES 54               // NTOT / BM
#define NTRI  (NTILES * (NTILES + 1) / 2)  // 1485; active = prefix triangle
#define KST   16                // K-steps: 1024 fp8 bytes / 64 B

typedef __attribute__((ext_vector_type(4))) float f32x4;

// ---------- prep + scan: offsets, meta, clab tail, accum+counter zero ----------
__global__ __launch_bounds__(256) void prepscan_kernel(const int* __restrict__ tgt,
                                                       int* __restrict__ offs,
                                                       int* __restrict__ meta,
                                                       int* __restrict__ clab,
                                                       float* __restrict__ accum,
                                                       int* __restrict__ counter) {
    int b = threadIdx.x;
    const int* t = tgt + b * TSLOT;
    int fz = 1;
    for (int i = 1; i < TSLOT; ++i) {
        if (t[i] == 0) { fz = i; break; }
    }
    __shared__ int sh[256];
    sh[b] = fz;
    __syncthreads();
    for (int d = 1; d < 256; d <<= 1) {
        int v = (b >= d) ? sh[b - d] : 0;
        __syncthreads();
        sh[b] += v;
        __syncthreads();
    }
    offs[b] = sh[b] - fz;  // exclusive
    if (b < 2) accum[b] = 0.0f;
    if (b == 2) *counter = 0;
    __syncthreads();
    int nv = sh[255];
    int npad = ((nv + 127) / 128) * 128;
    if (b == 255) {
        offs[256] = nv;
        meta[0] = nv;
        meta[1] = npad;
    }
    if (b < npad - nv) clab[nv + b] = -1;  // <= 127 entries
}

// ---------- wave-per-row L2-normalize f32 -> fp8 e4m3, scatter compacted ----------
__global__ __launch_bounds__(256) void norm_c_kernel(const float* __restrict__ in,
                                                     const int* __restrict__ tgt,
                                                     const int* __restrict__ offs,
                                                     unsigned char* __restrict__ cfb,
                                                     int* __restrict__ clab) {
    const int wv   = blockIdx.x * 4 + (threadIdx.x >> 6);
    const int lane = threadIdx.x & 63;
    const int b = wv / TSLOT, t = wv - b * TSLOT;
    const int o0 = offs[b], o1 = offs[b + 1];
    if (t >= o1 - o0) return;
    const int dest = o0 + t;
    const float* src = in + (size_t)wv * DIM + lane * 16;
    float4 v0 = *(const float4*)(src);
    float4 v1 = *(const float4*)(src + 4);
    float4 v2 = *(const float4*)(src + 8);
    float4 v3 = *(const float4*)(src + 12);
    float ss = v0.x*v0.x + v0.y*v0.y + v0.z*v0.z + v0.w*v0.w
             + v1.x*v1.x + v1.y*v1.y + v1.z*v1.z + v1.w*v1.w
             + v2.x*v2.x + v2.y*v2.y + v2.z*v2.z + v2.w*v2.w
             + v3.x*v3.x + v3.y*v3.y + v3.z*v3.z + v3.w*v3.w;
    #pragma unroll
    for (int off = 1; off < 64; off <<= 1) ss += __shfl_xor(ss, off);
    const float sc = 1.0f / fmaxf(sqrtf(ss), 1e-12f);
    float f[16] = {v0.x,v0.y,v0.z,v0.w, v1.x,v1.y,v1.z,v1.w,
                   v2.x,v2.y,v2.z,v2.w, v3.x,v3.y,v3.z,v3.w};
    uint4 o;
    unsigned int* ow = (unsigned int*)&o;
    #pragma unroll
    for (int q = 0; q < 4; ++q) {
        unsigned int u = 0;
        u = __builtin_amdgcn_cvt_pk_fp8_f32(f[q*4+0] * sc, f[q*4+1] * sc, u, 0);
        u = __builtin_amdgcn_cvt_pk_fp8_f32(f[q*4+2] * sc, f[q*4+3] * sc, u, 1);
        ow[q] = u;
    }
    *(uint4*)(cfb + (size_t)dest * DIM + lane * 16) = o;
    if (lane == 0) clab[dest] = tgt[wv];
}

// ---------- symmetric fused GEMM: fp8, 8 waves, 4-deep counted-vmcnt, BK=64 ----------
// Identical addressing/swizzle to the verified bf16-BK32 variant (rows are 64 B
// either way); staged bytes halve; mfma_f32_16x16x32_fp8_fp8 at bf16 rate.
__global__ __launch_bounds__(512) void gemm_kernel(const unsigned char* __restrict__ fb,
                                                   const int* __restrict__ clab,
                                                   const int* __restrict__ meta,
                                                   float* __restrict__ Ppos,
                                                   float* __restrict__ Pneg) {
    __shared__ __align__(16) char lds[65536];  // 4 bufs x (A 8KB + B 8KB)

    int t = blockIdx.x;
    int bi = 0;
    while (t >= NTILES - bi) { t -= NTILES - bi; ++bi; }
    const int bj = bi + t;
    const int npad = meta[1];
    const int col0 = bj * BM;
    if (col0 >= npad) return;
    const int row0 = bi * BM;
    const bool diag = (bi == bj);

    const int tid  = threadIdx.x;
    const int lane = tid & 63;
    const int w    = tid >> 6;         // 0..7
    const int wm   = w & 1;            // row strip (64 rows)
    const int wn   = w >> 1;           // col strip (32 cols)

    f32x4 acc[4][2] = {};
    const char* fbyte = (const char*)fb;

    // stage: A/B panels 128 rows x 64 B = 8 KB = 512 chunks; wave w: chunk w*64+lane
    auto stage = [&](int s) {
        char* buf = lds + (s & 3) * 16384;
        const int k0b = s * 64;
        const int c = w * 64 + lane;
        const int r = c >> 2, ks = c & 3;
        const int srcoff = ((ks ^ ((r >> 1) & 3)) << 4);
        const char* ga = fbyte + (size_t)(row0 + r) * DIM + k0b + srcoff;
        __builtin_amdgcn_global_load_lds(
            (const __attribute__((address_space(1))) void*)ga,
            (__attribute__((address_space(3))) void*)(buf + c * 16),
            16, 0, 0);
        const char* gb = fbyte + (size_t)(col0 + r) * DIM + k0b + srcoff;
        __builtin_amdgcn_global_load_lds(
            (const __attribute__((address_space(1))) void*)gb,
            (__attribute__((address_space(3))) void*)(buf + 8192 + c * 16),
            16, 0, 0);
    };

    const int rsel = lane & 15, tsl = lane >> 4;
    // swizzled LDS byte offset within a 64-B row for K-byte kb (8-aligned)
    auto swz = [&](int r, int kb) {
        int slot = (kb >> 4) & 3;
        return r * 64 + ((slot ^ ((r >> 1) & 3)) << 4) + (kb & 15);
    };
    auto compute = [&](int s) {
        const char* bA = lds + (s & 3) * 16384;
        const char* bB = bA + 8192;
        #pragma unroll
        for (int kk = 0; kk < 2; ++kk) {
            const int kb = kk * 32 + tsl * 8;
            long af[4], bf[2];
            #pragma unroll
            for (int m = 0; m < 4; ++m) {
                const int r = wm * 64 + m * 16 + rsel;
                af[m] = *(const long*)(bA + swz(r, kb));
            }
            #pragma unroll
            for (int n = 0; n < 2; ++n) {
                const int r = wn * 32 + n * 16 + rsel;
                bf[n] = *(const long*)(bB + swz(r, kb));
            }
            #pragma unroll
            for (int m = 0; m < 4; ++m)
                #pragma unroll
                for (int n = 0; n < 2; ++n)
                    acc[m][n] = __builtin_amdgcn_mfma_f32_16x16x32_fp8_fp8(
                        af[m], bf[n], acc[m][n], 0, 0, 0);
        }
    };

    stage(0); stage(1); stage(2);  // 6 loads/wave outstanding
    #pragma unroll 1
    for (int s = 0; s < KST - 3; ++s) {
        asm volatile("s_waitcnt vmcnt(4)" ::: "memory");   // own stage s landed
        __builtin_amdgcn_s_barrier();                      // all waves' stage s landed
        asm volatile("" ::: "memory");
        stage(s + 3);
        compute(s);
    }
    asm volatile("s_waitcnt vmcnt(4)" ::: "memory");
    __builtin_amdgcn_s_barrier();
    asm volatile("" ::: "memory");
    compute(KST - 3);
    asm volatile("s_waitcnt vmcnt(2)" ::: "memory");
    __builtin_amdgcn_s_barrier();
    asm volatile("" ::: "memory");
    compute(KST - 2);
    asm volatile("s_waitcnt vmcnt(0)" ::: "memory");
    __builtin_amdgcn_s_barrier();
    asm volatile("" ::: "memory");
    compute(KST - 1);

    // ---- epilogue: masked exp, cross-wave combine through LDS, coalesced stores ----
    // fl = buf0 (last read by compute(12); computes 13-15 read bufs 1-3) -> safe.
    const int c = rsel, g = tsl;
    float cpos[2] = {0, 0}, cneg[2] = {0, 0};
    float* fl = (float*)lds;

    #pragma unroll
    for (int m = 0; m < 4; ++m) {
        #pragma unroll
        for (int rg = 0; rg < 4; ++rg) {
            const int gi = row0 + wm * 64 + m * 16 + g * 4 + rg;
            const int li = clab[gi];
            float rp = 0.0f, rn = 0.0f;
            #pragma unroll
            for (int n = 0; n < 2; ++n) {
                const int gj = col0 + wn * 32 + n * 16 + c;
                const int lj = clab[gj];
                const float s = acc[m][n][rg];
                if (li >= 0 && lj >= 0) {
                    if (li == lj) { float e = __expf(-s); rp += e; cpos[n] += e; }
                    else          { float e = __expf(s);  rn += e; cneg[n] += e; }
                }
            }
            #pragma unroll
            for (int off = 1; off <= 8; off <<= 1) {
                rp += __shfl_xor(rp, off);
                rn += __shfl_xor(rn, off);
            }
            if (c == 0) {
                int lr = m * 16 + g * 4 + rg;          // 0..63
                fl[w * 64 + lr]        = rp;           // [0, 512)
                fl[512 + w * 64 + lr]  = rn;           // [512, 1024)
            }
        }
    }
    #pragma unroll
    for (int n = 0; n < 2; ++n) {
        float p = cpos[n], q = cneg[n];
        p += __shfl_xor(p, 16); p += __shfl_xor(p, 32);
        q += __shfl_xor(q, 16); q += __shfl_xor(q, 32);
        if (g == 0) {
            int lc = n * 16 + c;                       // 0..31
            fl[1024 + w * 32 + lc] = p;                // [1024, 1280)
            fl[1280 + w * 32 + lc] = q;                // [1280, 1536)
        }
    }
    __syncthreads();
    if (tid < 128) {
        // row credit: row strip sm = tid>>6; waves {sm, sm+2, sm+4, sm+6}
        int sm = tid >> 6, lr = tid & 63;
        float rp = 0.0f, rn = 0.0f;
        #pragma unroll
        for (int k = 0; k < 4; ++k) {
            rp += fl[(sm + 2 * k) * 64 + lr];
            rn += fl[512 + (sm + 2 * k) * 64 + lr];
        }
        int gi = row0 + tid;
        Ppos[(size_t)bj * NTOT + gi] = rp;   // slot bj (>= bi), coalesced
        Pneg[(size_t)bj * NTOT + gi] = rn;
    } else if (tid < 256 && !diag) {
        // col credit: col j; strip cn = j>>5; waves {cn*2, cn*2+1}
        int j = tid - 128, cn = j >> 5, lc = j & 31;
        float p = fl[1024 + (cn * 2) * 32 + lc] + fl[1024 + (cn * 2 + 1) * 32 + lc];
        float q = fl[1280 + (cn * 2) * 32 + lc] + fl[1280 + (cn * 2 + 1) * 32 + lc];
        int gj = col0 + j;
        Ppos[(size_t)bi * NTOT + gj] = p;    // slot bi (< bj), coalesced
        Pneg[(size_t)bi * NTOT + gj] = q;
    }
}

// ---------- finalize: gather partials, masked mean, last block writes out ----------
__global__ __launch_bounds__(256) void finalize_kernel(const int* __restrict__ clab,
                                                       const int* __restrict__ meta,
                                                       const float* __restrict__ Ppos,
                                                       const float* __restrict__ Pneg,
                                                       float* __restrict__ accum,
                                                       int* __restrict__ counter,
                                                       float* __restrict__ out) {
    int i = blockIdx.x * blockDim.x + threadIdx.x;
    const int npad = meta[1];
    const int nta = npad >> 7;
    float s = 0.0f, cnt = 0.0f;
    if (i < npad && clab[i] >= 0) {
        float sp = 0.0f, sn = 0.0f;
        for (int t = 0; t < nta; ++t) {
            sp += Ppos[(size_t)t * NTOT + i];
            sn += Pneg[(size_t)t * NTOT + i];
        }
        s = log1pf(sp * sn);
        cnt = 1.0f;
    }
    #pragma unroll
    for (int off = 1; off < 64; off <<= 1) {
        s   += __shfl_xor(s, off);
        cnt += __shfl_xor(cnt, off);
    }
    __shared__ float sh[8];
    int lane = threadIdx.x & 63, w = threadIdx.x >> 6;
    if (lane == 0) { sh[w] = s; sh[4 + w] = cnt; }
    __syncthreads();
    if (threadIdx.x == 0) {
        atomicAdd(&accum[0], sh[0] + sh[1] + sh[2] + sh[3]);
        atomicAdd(&accum[1], sh[4] + sh[5] + sh[6] + sh[7]);
        __threadfence();
        int done = atomicAdd(counter, 1);
        if (done == (int)gridDim.x - 1) {
            __threadfence();
            out[0] = accum[0] / accum[1];
        }
    }
}

extern "C" void kernel_launch(void* const* d_in, const int* in_sizes, int n_in,
                              void* d_out, int out_size, void* d_ws, size_t ws_size,
                              hipStream_t stream) {
    (void)in_sizes; (void)n_in; (void)out_size; (void)ws_size;
    const float* input_f = (const float*)d_in[0];
    const int*   target  = (const int*)d_in[1];
    float* out = (float*)d_out;

    char* ws = (char*)d_ws;
    const size_t FB_BYTES = (size_t)NTOT * DIM;          // 7,077,888 (fp8)
    unsigned char* cfb = (unsigned char*)ws;
    char* p = ws + FB_BYTES;
    int*   clab  = (int*)p;            p += NTOT * 4;
    int*   offs  = (int*)p;            p += 4096;
    int*   meta  = (int*)p;            p += 256;
    float* accum = (float*)p;          p += 128;
    int*   counter = (int*)p;          p += 128;
    float* Ppos  = (float*)p;          p += (size_t)NTILES * NTOT * 4;  // 1.49 MB
    float* Pneg  = (float*)p;

    prepscan_kernel<<<dim3(1), dim3(256), 0, stream>>>(target, offs, meta, clab, accum, counter);
    norm_c_kernel<<<dim3(NTOT / 4), dim3(256), 0, stream>>>(input_f, target, offs, cfb, clab);
    gemm_kernel<<<dim3(NTRI), dim3(512), 0, stream>>>(cfb, clab, meta, Ppos, Pneg);
    finalize_kernel<<<dim3((NTOT + 255) / 256), dim3(256), 0, stream>>>(clab, meta, Ppos, Pneg, accum, counter, out);
}

// Round 9
// 56.386 us; speedup vs baseline: 2.3611x; 1.2380x over previous
//
#include <hip/hip_runtime.h>
#include <hip/hip_bf16.h>
#include <stdint.h>

#define BATCH 256
#define TSLOT 27
#define NTOT  (BATCH * TSLOT)   // 6912
#define DIM   1024
#define BM    128
#define NTILES 54               // NTOT / BM
#define NTRI  (NTILES * (NTILES + 1) / 2)  // 1485; active = prefix triangle
#define KST   16                // K-steps: 1024 fp8 bytes / 64 B

typedef __attribute__((ext_vector_type(4))) float f32x4;
typedef __attribute__((ext_vector_type(2))) long l64x2;

// ---------- prep + scan: offsets, meta, clab tail, accum+counter zero ----------
__global__ __launch_bounds__(256) void prepscan_kernel(const int* __restrict__ tgt,
                                                       int* __restrict__ offs,
                                                       int* __restrict__ meta,
                                                       int* __restrict__ clab,
                                                       float* __restrict__ accum,
                                                       int* __restrict__ counter) {
    int b = threadIdx.x;
    const int* t = tgt + b * TSLOT;
    int fz = 1;
    for (int i = 1; i < TSLOT; ++i) {
        if (t[i] == 0) { fz = i; break; }
    }
    __shared__ int sh[256];
    sh[b] = fz;
    __syncthreads();
    for (int d = 1; d < 256; d <<= 1) {
        int v = (b >= d) ? sh[b - d] : 0;
        __syncthreads();
        sh[b] += v;
        __syncthreads();
    }
    offs[b] = sh[b] - fz;  // exclusive
    if (b < 2) accum[b] = 0.0f;
    if (b == 2) *counter = 0;
    __syncthreads();
    int nv = sh[255];
    int npad = ((nv + 127) / 128) * 128;
    if (b == 255) {
        offs[256] = nv;
        meta[0] = nv;
        meta[1] = npad;
    }
    if (b < npad - nv) clab[nv + b] = -1;  // <= 127 entries
}

// ---------- wave-per-row L2-normalize f32 -> fp8 e4m3, scatter compacted ----------
__global__ __launch_bounds__(256) void norm_c_kernel(const float* __restrict__ in,
                                                     const int* __restrict__ tgt,
                                                     const int* __restrict__ offs,
                                                     unsigned char* __restrict__ cfb,
                                                     int* __restrict__ clab) {
    const int wv   = blockIdx.x * 4 + (threadIdx.x >> 6);
    const int lane = threadIdx.x & 63;
    const int b = wv / TSLOT, t = wv - b * TSLOT;
    const int o0 = offs[b], o1 = offs[b + 1];
    if (t >= o1 - o0) return;
    const int dest = o0 + t;
    const float* src = in + (size_t)wv * DIM + lane * 16;
    float4 v0 = *(const float4*)(src);
    float4 v1 = *(const float4*)(src + 4);
    float4 v2 = *(const float4*)(src + 8);
    float4 v3 = *(const float4*)(src + 12);
    float ss = v0.x*v0.x + v0.y*v0.y + v0.z*v0.z + v0.w*v0.w
             + v1.x*v1.x + v1.y*v1.y + v1.z*v1.z + v1.w*v1.w
             + v2.x*v2.x + v2.y*v2.y + v2.z*v2.z + v2.w*v2.w
             + v3.x*v3.x + v3.y*v3.y + v3.z*v3.z + v3.w*v3.w;
    #pragma unroll
    for (int off = 1; off < 64; off <<= 1) ss += __shfl_xor(ss, off);
    const float sc = 1.0f / fmaxf(sqrtf(ss), 1e-12f);
    float f[16] = {v0.x,v0.y,v0.z,v0.w, v1.x,v1.y,v1.z,v1.w,
                   v2.x,v2.y,v2.z,v2.w, v3.x,v3.y,v3.z,v3.w};
    uint4 o;
    unsigned int* ow = (unsigned int*)&o;
    #pragma unroll
    for (int q = 0; q < 4; ++q) {
        unsigned int u = 0;
        u = __builtin_amdgcn_cvt_pk_fp8_f32(f[q*4+0] * sc, f[q*4+1] * sc, u, 0);
        u = __builtin_amdgcn_cvt_pk_fp8_f32(f[q*4+2] * sc, f[q*4+3] * sc, u, 1);
        ow[q] = u;
    }
    *(uint4*)(cfb + (size_t)dest * DIM + lane * 16) = o;
    if (lane == 0) clab[dest] = tgt[wv];
}

// ---------- symmetric fused GEMM: fp8, 8 waves, 3-buf depth-2, BK=64 ----------
// Fragment reads are single ds_read_b128 per row: K-window kk maps to the
// low/high 8 bytes of lane tsl's 16-B slot (same permutation for A and B,
// so the dot product is unchanged). Conflict-free: per row the 4 tsl-lanes
// cover all 4 swizzled slots; 8 rows per bank-half -> 8 distinct words/bank.
__global__ __launch_bounds__(512) void gemm_kernel(const unsigned char* __restrict__ fb,
                                                   const int* __restrict__ clab,
                                                   const int* __restrict__ meta,
                                                   float* __restrict__ Ppos,
                                                   float* __restrict__ Pneg) {
    __shared__ __align__(16) char lds[49152];  // 3 bufs x (A 8KB + B 8KB)

    int t = blockIdx.x;
    int bi = 0;
    while (t >= NTILES - bi) { t -= NTILES - bi; ++bi; }
    const int bj = bi + t;
    const int npad = meta[1];
    const int col0 = bj * BM;
    if (col0 >= npad) return;
    const int row0 = bi * BM;
    const bool diag = (bi == bj);

    const int tid  = threadIdx.x;
    const int lane = tid & 63;
    const int w    = tid >> 6;         // 0..7
    const int wm   = w & 1;            // row strip (64 rows)
    const int wn   = w >> 1;           // col strip (32 cols)

    f32x4 acc[4][2] = {};
    const char* fbyte = (const char*)fb;

    // stage: A/B panels 128 rows x 64 B = 8 KB = 512 chunks; wave w: chunk w*64+lane
    auto stage = [&](int s) {
        char* buf = lds + (s % 3) * 16384;
        const int k0b = s * 64;
        const int c = w * 64 + lane;
        const int r = c >> 2, ks = c & 3;
        const int srcoff = ((ks ^ ((r >> 1) & 3)) << 4);
        const char* ga = fbyte + (size_t)(row0 + r) * DIM + k0b + srcoff;
        __builtin_amdgcn_global_load_lds(
            (const __attribute__((address_space(1))) void*)ga,
            (__attribute__((address_space(3))) void*)(buf + c * 16),
            16, 0, 0);
        const char* gb = fbyte + (size_t)(col0 + r) * DIM + k0b + srcoff;
        __builtin_amdgcn_global_load_lds(
            (const __attribute__((address_space(1))) void*)gb,
            (__attribute__((address_space(3))) void*)(buf + 8192 + c * 16),
            16, 0, 0);
    };

    const int rsel = lane & 15, tsl = lane >> 4;
    auto compute = [&](int s) {
        const char* bA = lds + (s % 3) * 16384;
        const char* bB = bA + 8192;
        l64x2 av[4], bv[2];
        #pragma unroll
        for (int m = 0; m < 4; ++m) {
            const int r = wm * 64 + m * 16 + rsel;
            av[m] = *(const l64x2*)(bA + r * 64 + ((tsl ^ ((r >> 1) & 3)) << 4));
        }
        #pragma unroll
        for (int n = 0; n < 2; ++n) {
            const int r = wn * 32 + n * 16 + rsel;
            bv[n] = *(const l64x2*)(bB + r * 64 + ((tsl ^ ((r >> 1) & 3)) << 4));
        }
        #pragma unroll
        for (int kk = 0; kk < 2; ++kk)
            #pragma unroll
            for (int m = 0; m < 4; ++m)
                #pragma unroll
                for (int n = 0; n < 2; ++n)
                    acc[m][n] = __builtin_amdgcn_mfma_f32_16x16x32_fp8_fp8(
                        av[m][kk], bv[n][kk], acc[m][n], 0, 0, 0);
    };

    stage(0); stage(1);  // 4 loads/wave outstanding
    #pragma unroll 1
    for (int s = 0; s < KST - 2; ++s) {
        asm volatile("s_waitcnt vmcnt(2)" ::: "memory");   // own stage s landed
        __builtin_amdgcn_s_barrier();                      // all waves' stage s landed
        asm volatile("" ::: "memory");
        stage(s + 2);                                      // buf (s-1)%3: all past compute(s-1)
        compute(s);
    }
    asm volatile("s_waitcnt vmcnt(2)" ::: "memory");
    __builtin_amdgcn_s_barrier();
    asm volatile("" ::: "memory");
    compute(KST - 2);
    asm volatile("s_waitcnt vmcnt(0)" ::: "memory");
    __builtin_amdgcn_s_barrier();
    asm volatile("" ::: "memory");
    compute(KST - 1);

    // ---- epilogue: masked exp, cross-wave combine through LDS, coalesced stores ----
    // scratch = buf1 (16384..): last read by compute(13), and every wave passed the
    // barrier after that; buf0 is still read by compute(15) so don't touch it.
    const int c = rsel, g = tsl;
    float cpos[2] = {0, 0}, cneg[2] = {0, 0};
    float* fl = (float*)(lds + 16384);

    #pragma unroll
    for (int m = 0; m < 4; ++m) {
        #pragma unroll
        for (int rg = 0; rg < 4; ++rg) {
            const int gi = row0 + wm * 64 + m * 16 + g * 4 + rg;
            const int li = clab[gi];
            float rp = 0.0f, rn = 0.0f;
            #pragma unroll
            for (int n = 0; n < 2; ++n) {
                const int gj = col0 + wn * 32 + n * 16 + c;
                const int lj = clab[gj];
                const float s = acc[m][n][rg];
                if (li >= 0 && lj >= 0) {
                    if (li == lj) { float e = __expf(-s); rp += e; cpos[n] += e; }
                    else          { float e = __expf(s);  rn += e; cneg[n] += e; }
                }
            }
            #pragma unroll
            for (int off = 1; off <= 8; off <<= 1) {
                rp += __shfl_xor(rp, off);
                rn += __shfl_xor(rn, off);
            }
            if (c == 0) {
                int lr = m * 16 + g * 4 + rg;          // 0..63
                fl[w * 64 + lr]        = rp;           // [0, 512)
                fl[512 + w * 64 + lr]  = rn;           // [512, 1024)
            }
        }
    }
    #pragma unroll
    for (int n = 0; n < 2; ++n) {
        float p = cpos[n], q = cneg[n];
        p += __shfl_xor(p, 16); p += __shfl_xor(p, 32);
        q += __shfl_xor(q, 16); q += __shfl_xor(q, 32);
        if (g == 0) {
            int lc = n * 16 + c;                       // 0..31
            fl[1024 + w * 32 + lc] = p;                // [1024, 1280)
            fl[1280 + w * 32 + lc] = q;                // [1280, 1536)
        }
    }
    __syncthreads();
    if (tid < 128) {
        // row credit: row strip sm = tid>>6; waves {sm, sm+2, sm+4, sm+6}
        int sm = tid >> 6, lr = tid & 63;
        float rp = 0.0f, rn = 0.0f;
        #pragma unroll
        for (int k = 0; k < 4; ++k) {
            rp += fl[(sm + 2 * k) * 64 + lr];
            rn += fl[512 + (sm + 2 * k) * 64 + lr];
        }
        int gi = row0 + tid;
        Ppos[(size_t)bj * NTOT + gi] = rp;   // slot bj (>= bi), coalesced
        Pneg[(size_t)bj * NTOT + gi] = rn;
    } else if (tid < 256 && !diag) {
        // col credit: col j; strip cn = j>>5; waves {cn*2, cn*2+1}
        int j = tid - 128, cn = j >> 5, lc = j & 31;
        float p = fl[1024 + (cn * 2) * 32 + lc] + fl[1024 + (cn * 2 + 1) * 32 + lc];
        float q = fl[1280 + (cn * 2) * 32 + lc] + fl[1280 + (cn * 2 + 1) * 32 + lc];
        int gj = col0 + j;
        Ppos[(size_t)bi * NTOT + gj] = p;    // slot bi (< bj), coalesced
        Pneg[(size_t)bi * NTOT + gj] = q;
    }
}

// ---------- finalize: gather partials, masked mean, last block writes out ----------
__global__ __launch_bounds__(256) void finalize_kernel(const int* __restrict__ clab,
                                                       const int* __restrict__ meta,
                                                       const float* __restrict__ Ppos,
                                                       const float* __restrict__ Pneg,
                                                       float* __restrict__ accum,
                                                       int* __restrict__ counter,
                                                       float* __restrict__ out) {
    int i = blockIdx.x * blockDim.x + threadIdx.x;
    const int npad = meta[1];
    const int nta = npad >> 7;
    float s = 0.0f, cnt = 0.0f;
    if (i < npad && clab[i] >= 0) {
        float sp = 0.0f, sn = 0.0f;
        for (int t = 0; t < nta; ++t) {
            sp += Ppos[(size_t)t * NTOT + i];
            sn += Pneg[(size_t)t * NTOT + i];
        }
        s = log1pf(sp * sn);
        cnt = 1.0f;
    }
    #pragma unroll
    for (int off = 1; off < 64; off <<= 1) {
        s   += __shfl_xor(s, off);
        cnt += __shfl_xor(cnt, off);
    }
    __shared__ float sh[8];
    int lane = threadIdx.x & 63, w = threadIdx.x >> 6;
    if (lane == 0) { sh[w] = s; sh[4 + w] = cnt; }
    __syncthreads();
    if (threadIdx.x == 0) {
        atomicAdd(&accum[0], sh[0] + sh[1] + sh[2] + sh[3]);
        atomicAdd(&accum[1], sh[4] + sh[5] + sh[6] + sh[7]);
        __threadfence();
        int done = atomicAdd(counter, 1);
        if (done == (int)gridDim.x - 1) {
            __threadfence();
            out[0] = accum[0] / accum[1];
        }
    }
}

extern "C" void kernel_launch(void* const* d_in, const int* in_sizes, int n_in,
                              void* d_out, int out_size, void* d_ws, size_t ws_size,
                              hipStream_t stream) {
    (void)in_sizes; (void)n_in; (void)out_size; (void)ws_size;
    const float* input_f = (const float*)d_in[0];
    const int*   target  = (const int*)d_in[1];
    float* out = (float*)d_out;

    char* ws = (char*)d_ws;
    const size_t FB_BYTES = (size_t)NTOT * DIM;          // 7,077,888 (fp8)
    unsigned char* cfb = (unsigned char*)ws;
    char* p = ws + FB_BYTES;
    int*   clab  = (int*)p;            p += NTOT * 4;
    int*   offs  = (int*)p;            p += 4096;
    int*   meta  = (int*)p;            p += 256;
    float* accum = (float*)p;          p += 128;
    int*   counter = (int*)p;          p += 128;
    float* Ppos  = (float*)p;          p += (size_t)NTILES * NTOT * 4;  // 1.49 MB
    float* Pneg  = (float*)p;

    prepscan_kernel<<<dim3(1), dim3(256), 0, stream>>>(target, offs, meta, clab, accum, counter);
    norm_c_kernel<<<dim3(NTOT / 4), dim3(256), 0, stream>>>(input_f, target, offs, cfb, clab);
    gemm_kernel<<<dim3(NTRI), dim3(512), 0, stream>>>(cfb, clab, meta, Ppos, Pneg);
    finalize_kernel<<<dim3((NTOT + 255) / 256), dim3(256), 0, stream>>>(clab, meta, Ppos, Pneg, accum, counter, out);
}

// Round 10
// 51.020 us; speedup vs baseline: 2.6094x; 1.1052x over previous
//
#include <hip/hip_runtime.h>
#include <hip/hip_bf16.h>
#include <stdint.h>

#define BATCH 256
#define TSLOT 27
#define NTOT  (BATCH * TSLOT)   // 6912
#define DIM   1024
#define TS    192               // tile size
#define NSMAX 36                // max strips (NTOT/TS)
#define NTRIMAX (NSMAX * (NSMAX + 1) / 2)  // 666
#define KST   16                // K-steps: 1024 fp8 bytes / 64 B
#define BUFSZ 24576             // per-step LDS: A 12K + B 12K

typedef __attribute__((ext_vector_type(4))) float f32x4;
typedef __attribute__((ext_vector_type(2))) long l64x2;

// ---------- prep + scan: offsets, meta, clab tail, accum+counter zero ----------
__global__ __launch_bounds__(256) void prepscan_kernel(const int* __restrict__ tgt,
                                                       int* __restrict__ offs,
                                                       int* __restrict__ meta,
                                                       int* __restrict__ clab,
                                                       float* __restrict__ accum,
                                                       int* __restrict__ counter) {
    int b = threadIdx.x;
    const int* t = tgt + b * TSLOT;
    int fz = 1;
    for (int i = 1; i < TSLOT; ++i) {
        if (t[i] == 0) { fz = i; break; }
    }
    __shared__ int sh[256];
    sh[b] = fz;
    __syncthreads();
    for (int d = 1; d < 256; d <<= 1) {
        int v = (b >= d) ? sh[b - d] : 0;
        __syncthreads();
        sh[b] += v;
        __syncthreads();
    }
    offs[b] = sh[b] - fz;  // exclusive
    if (b < 2) accum[b] = 0.0f;
    if (b == 2) *counter = 0;
    __syncthreads();
    int nv = sh[255];
    int npad = ((nv + TS - 1) / TS) * TS;
    if (b == 255) {
        offs[256] = nv;
        meta[0] = nv;
        meta[1] = npad;
    }
    if (b < npad - nv) clab[nv + b] = -1;  // <= 191 entries
}

// ---------- wave-per-row L2-normalize f32 -> fp8 e4m3, scatter compacted ----------
__global__ __launch_bounds__(256) void norm_c_kernel(const float* __restrict__ in,
                                                     const int* __restrict__ tgt,
                                                     const int* __restrict__ offs,
                                                     unsigned char* __restrict__ cfb,
                                                     int* __restrict__ clab) {
    const int wv   = blockIdx.x * 4 + (threadIdx.x >> 6);
    const int lane = threadIdx.x & 63;
    const int b = wv / TSLOT, t = wv - b * TSLOT;
    const int o0 = offs[b], o1 = offs[b + 1];
    if (t >= o1 - o0) return;
    const int dest = o0 + t;
    const float* src = in + (size_t)wv * DIM + lane * 16;
    float4 v0 = *(const float4*)(src);
    float4 v1 = *(const float4*)(src + 4);
    float4 v2 = *(const float4*)(src + 8);
    float4 v3 = *(const float4*)(src + 12);
    float ss = v0.x*v0.x + v0.y*v0.y + v0.z*v0.z + v0.w*v0.w
             + v1.x*v1.x + v1.y*v1.y + v1.z*v1.z + v1.w*v1.w
             + v2.x*v2.x + v2.y*v2.y + v2.z*v2.z + v2.w*v2.w
             + v3.x*v3.x + v3.y*v3.y + v3.z*v3.z + v3.w*v3.w;
    #pragma unroll
    for (int off = 1; off < 64; off <<= 1) ss += __shfl_xor(ss, off);
    const float sc = 1.0f / fmaxf(sqrtf(ss), 1e-12f);
    float f[16] = {v0.x,v0.y,v0.z,v0.w, v1.x,v1.y,v1.z,v1.w,
                   v2.x,v2.y,v2.z,v2.w, v3.x,v3.y,v3.z,v3.w};
    uint4 o;
    unsigned int* ow = (unsigned int*)&o;
    #pragma unroll
    for (int q = 0; q < 4; ++q) {
        unsigned int u = 0;
        u = __builtin_amdgcn_cvt_pk_fp8_f32(f[q*4+0] * sc, f[q*4+1] * sc, u, 0);
        u = __builtin_amdgcn_cvt_pk_fp8_f32(f[q*4+2] * sc, f[q*4+3] * sc, u, 1);
        ow[q] = u;
    }
    *(uint4*)(cfb + (size_t)dest * DIM + lane * 16) = o;
    if (lane == 0) clab[dest] = tgt[wv];
}

// ---------- symmetric fused GEMM: fp8, 192-tile, 8 waves, 4-buf depth-3 ----------
// Prefix-aware bijective XCD swizzle (computed from meta): XCD x gets a
// contiguous run of triangle indices -> A-panel L2 locality; balanced for
// any data-dependent active count.
__global__ __launch_bounds__(512) void gemm_kernel(const unsigned char* __restrict__ fb,
                                                   const int* __restrict__ clab,
                                                   const int* __restrict__ meta,
                                                   float* __restrict__ Ppos,
                                                   float* __restrict__ Pneg) {
    __shared__ __align__(16) char lds[4 * BUFSZ];  // 96 KB

    const int npad = meta[1];
    const int nstrips = npad / TS;
    const int nact = nstrips * (nstrips + 1) / 2;
    const int k = blockIdx.x >> 3, x = blockIdx.x & 7;
    const int q8 = nact >> 3, r8 = nact & 7;
    const int cnt = q8 + (x < r8 ? 1 : 0);
    if (k >= cnt) return;
    int t = x * q8 + (x < r8 ? x : r8) + k;
    int bi = 0;
    while (t >= nstrips - bi) { t -= nstrips - bi; ++bi; }
    const int bj = bi + t;
    const int row0 = bi * TS;
    const int col0 = bj * TS;
    const bool diag = (bi == bj);

    const int tid  = threadIdx.x;
    const int lane = tid & 63;
    const int w    = tid >> 6;         // 0..7
    const int wm   = w >> 2;           // row strip (96 rows)
    const int wn   = w & 3;            // col strip (48 cols)

    f32x4 acc[6][3] = {};
    const char* fbyte = (const char*)fb;

    // stage: A panel rows [row0,row0+192) and B panel rows [col0,col0+192),
    // 64 B per row per step; 1536 16-B chunks; wave w covers c = w*192+j*64+lane.
    auto stage = [&](int s) {
        char* buf = lds + (s & 3) * BUFSZ;
        const int k0b = s * 64;
        #pragma unroll
        for (int j = 0; j < 3; ++j) {
            const int c = w * 192 + j * 64 + lane;          // 0..1535
            const int cc = (c >= 768) ? c - 768 : c;
            const int base = (c >= 768) ? col0 : row0;
            const int r = cc >> 2, ks = cc & 3;
            const int srcoff = ((ks ^ ((r >> 1) & 3)) << 4);
            const char* g = fbyte + (size_t)(base + r) * DIM + k0b + srcoff;
            __builtin_amdgcn_global_load_lds(
                (const __attribute__((address_space(1))) void*)g,
                (__attribute__((address_space(3))) void*)(buf + c * 16),
                16, 0, 0);
        }
    };

    const int rsel = lane & 15, tsl = lane >> 4;
    auto compute = [&](int s) {
        const char* bA = lds + (s & 3) * BUFSZ;
        const char* bB = bA + 12288;
        l64x2 av[6], bv[3];
        #pragma unroll
        for (int m = 0; m < 6; ++m) {
            const int r = wm * 96 + m * 16 + rsel;
            av[m] = *(const l64x2*)(bA + r * 64 + ((tsl ^ ((r >> 1) & 3)) << 4));
        }
        #pragma unroll
        for (int n = 0; n < 3; ++n) {
            const int r = wn * 48 + n * 16 + rsel;
            bv[n] = *(const l64x2*)(bB + r * 64 + ((tsl ^ ((r >> 1) & 3)) << 4));
        }
        #pragma unroll
        for (int kk = 0; kk < 2; ++kk)
            #pragma unroll
            for (int m = 0; m < 6; ++m)
                #pragma unroll
                for (int n = 0; n < 3; ++n)
                    acc[m][n] = __builtin_amdgcn_mfma_f32_16x16x32_fp8_fp8(
                        av[m][kk], bv[n][kk], acc[m][n], 0, 0, 0);
    };

    stage(0); stage(1); stage(2);  // 9 loads/wave outstanding
    #pragma unroll 1
    for (int s = 0; s < KST - 3; ++s) {
        asm volatile("s_waitcnt vmcnt(6)" ::: "memory");   // own stage s landed
        __builtin_amdgcn_s_barrier();                      // all waves' stage s landed
        asm volatile("" ::: "memory");
        stage(s + 3);                                      // buf (s-1)&3: all past compute(s-1)
        compute(s);
    }
    asm volatile("s_waitcnt vmcnt(6)" ::: "memory");
    __builtin_amdgcn_s_barrier();
    asm volatile("" ::: "memory");
    compute(KST - 3);
    asm volatile("s_waitcnt vmcnt(3)" ::: "memory");
    __builtin_amdgcn_s_barrier();
    asm volatile("" ::: "memory");
    compute(KST - 2);
    asm volatile("s_waitcnt vmcnt(0)" ::: "memory");
    __builtin_amdgcn_s_barrier();
    asm volatile("" ::: "memory");
    compute(KST - 1);

    // ---- epilogue: masked exp, cross-wave combine through LDS, coalesced stores ----
    // scratch = buf0: last read by compute(12); barrier before compute(13)
    // put every wave past it; computes 13/14/15 read bufs 1/2/3 -> disjoint.
    const int c = rsel, g = tsl;
    float cpos[3] = {0, 0, 0}, cneg[3] = {0, 0, 0};
    float* fl = (float*)lds;

    #pragma unroll
    for (int m = 0; m < 6; ++m) {
        #pragma unroll
        for (int rg = 0; rg < 4; ++rg) {
            const int gi = row0 + wm * 96 + m * 16 + g * 4 + rg;
            const int li = clab[gi];
            float rp = 0.0f, rn = 0.0f;
            #pragma unroll
            for (int n = 0; n < 3; ++n) {
                const int gj = col0 + wn * 48 + n * 16 + c;
                const int lj = clab[gj];
                const float s = acc[m][n][rg];
                if (li >= 0 && lj >= 0) {
                    if (li == lj) { float e = __expf(-s); rp += e; cpos[n] += e; }
                    else          { float e = __expf(s);  rn += e; cneg[n] += e; }
                }
            }
            #pragma unroll
            for (int off = 1; off <= 8; off <<= 1) {
                rp += __shfl_xor(rp, off);
                rn += __shfl_xor(rn, off);
            }
            if (c == 0) {
                int lr = m * 16 + g * 4 + rg;          // 0..95
                fl[w * 96 + lr]        = rp;           // [0, 768)
                fl[768 + w * 96 + lr]  = rn;           // [768, 1536)
            }
        }
    }
    #pragma unroll
    for (int n = 0; n < 3; ++n) {
        float p = cpos[n], q = cneg[n];
        p += __shfl_xor(p, 16); p += __shfl_xor(p, 32);
        q += __shfl_xor(q, 16); q += __shfl_xor(q, 32);
        if (g == 0) {
            int lc = n * 16 + c;                       // 0..47
            fl[1536 + w * 48 + lc] = p;                // [1536, 1920)
            fl[1920 + w * 48 + lc] = q;                // [1920, 2304)
        }
    }
    __syncthreads();
    if (tid < 192) {
        // row credit: strip sm = tid/96; combine col-waves {sm*4 + 0..3}
        int sm = tid / 96, lr = tid % 96;
        float rp = 0.0f, rn = 0.0f;
        #pragma unroll
        for (int kk = 0; kk < 4; ++kk) {
            rp += fl[(sm * 4 + kk) * 96 + lr];
            rn += fl[768 + (sm * 4 + kk) * 96 + lr];
        }
        int gi = row0 + tid;
        Ppos[(size_t)bj * NTOT + gi] = rp;   // slot bj (>= bi), coalesced
        Pneg[(size_t)bj * NTOT + gi] = rn;
    } else if (tid < 384 && !diag) {
        // col credit: j = tid-192; strip cn = j/48; combine row-waves {cn, 4+cn}
        int j = tid - 192, cn = j / 48, lc = j % 48;
        float p = fl[1536 + cn * 48 + lc] + fl[1536 + (4 + cn) * 48 + lc];
        float q = fl[1920 + cn * 48 + lc] + fl[1920 + (4 + cn) * 48 + lc];
        int gj = col0 + j;
        Ppos[(size_t)bi * NTOT + gj] = p;    // slot bi (< bj), coalesced
        Pneg[(size_t)bi * NTOT + gj] = q;
    }
}

// ---------- finalize: gather partials, masked mean, last block writes out ----------
__global__ __launch_bounds__(256) void finalize_kernel(const int* __restrict__ clab,
                                                       const int* __restrict__ meta,
                                                       const float* __restrict__ Ppos,
                                                       const float* __restrict__ Pneg,
                                                       float* __restrict__ accum,
                                                       int* __restrict__ counter,
                                                       float* __restrict__ out) {
    int i = blockIdx.x * blockDim.x + threadIdx.x;
    const int npad = meta[1];
    const int nta = npad / TS;
    float s = 0.0f, cnt = 0.0f;
    if (i < npad && clab[i] >= 0) {
        float sp = 0.0f, sn = 0.0f;
        for (int t = 0; t < nta; ++t) {
            sp += Ppos[(size_t)t * NTOT + i];
            sn += Pneg[(size_t)t * NTOT + i];
        }
        s = log1pf(sp * sn);
        cnt = 1.0f;
    }
    #pragma unroll
    for (int off = 1; off < 64; off <<= 1) {
        s   += __shfl_xor(s, off);
        cnt += __shfl_xor(cnt, off);
    }
    __shared__ float sh[8];
    int lane = threadIdx.x & 63, w = threadIdx.x >> 6;
    if (lane == 0) { sh[w] = s; sh[4 + w] = cnt; }
    __syncthreads();
    if (threadIdx.x == 0) {
        atomicAdd(&accum[0], sh[0] + sh[1] + sh[2] + sh[3]);
        atomicAdd(&accum[1], sh[4] + sh[5] + sh[6] + sh[7]);
        __threadfence();
        int done = atomicAdd(counter, 1);
        if (done == (int)gridDim.x - 1) {
            __threadfence();
            out[0] = accum[0] / accum[1];
        }
    }
}

extern "C" void kernel_launch(void* const* d_in, const int* in_sizes, int n_in,
                              void* d_out, int out_size, void* d_ws, size_t ws_size,
                              hipStream_t stream) {
    (void)in_sizes; (void)n_in; (void)out_size; (void)ws_size;
    const float* input_f = (const float*)d_in[0];
    const int*   target  = (const int*)d_in[1];
    float* out = (float*)d_out;

    char* ws = (char*)d_ws;
    const size_t FB_BYTES = (size_t)NTOT * DIM;          // 7,077,888 (fp8)
    unsigned char* cfb = (unsigned char*)ws;
    char* p = ws + FB_BYTES;
    int*   clab  = (int*)p;            p += NTOT * 4;
    int*   offs  = (int*)p;            p += 4096;
    int*   meta  = (int*)p;            p += 256;
    float* accum = (float*)p;          p += 128;
    int*   counter = (int*)p;          p += 128;
    float* Ppos  = (float*)p;          p += (size_t)NSMAX * NTOT * 4;  // 995 KB
    float* Pneg  = (float*)p;

    prepscan_kernel<<<dim3(1), dim3(256), 0, stream>>>(target, offs, meta, clab, accum, counter);
    norm_c_kernel<<<dim3(NTOT / 4), dim3(256), 0, stream>>>(input_f, target, offs, cfb, clab);
    gemm_kernel<<<dim3(NTRIMAX), dim3(512), 0, stream>>>(cfb, clab, meta, Ppos, Pneg);
    finalize_kernel<<<dim3((NTOT + 255) / 256), dim3(256), 0, stream>>>(clab, meta, Ppos, Pneg, accum, counter, out);
}

// Round 11
// 48.154 us; speedup vs baseline: 2.7648x; 1.0595x over previous
//
#include <hip/hip_runtime.h>
#include <hip/hip_bf16.h>
#include <stdint.h>

#define BATCH 256
#define TSLOT 27
#define NTOT  (BATCH * TSLOT)   // 6912
#define DIM   1024
#define TS    192               // tile size
#define NSMAX 36                // max strips (NTOT/TS)
#define NTRIMAX (NSMAX * (NSMAX + 1) / 2)  // 666
#define KST   16                // K-steps: 1024 fp8 bytes / 64 B
#define BUFSZ 24576             // per-step LDS: A 12K + B 12K

typedef __attribute__((ext_vector_type(4))) float f32x4;
typedef __attribute__((ext_vector_type(2))) long l64x2;

// ---------- fused prep + norm: every block redundantly computes the sample-length
// scan (targets are L2-hot, scan is block-local), then 4 waves normalize 4 rows.
// Removes the serial 1-block prepscan kernel and one launch gap entirely. ----------
__global__ __launch_bounds__(256) void prep_norm_kernel(const float* __restrict__ in,
                                                        const int* __restrict__ tgt,
                                                        unsigned char* __restrict__ cfb,
                                                        int* __restrict__ clab,
                                                        int* __restrict__ meta,
                                                        float* __restrict__ accum,
                                                        int* __restrict__ counter) {
    __shared__ int shs[256];   // inclusive scan of fz
    __shared__ int shf[256];   // fz per sample
    const int b = threadIdx.x;
    {
        const int* t = tgt + b * TSLOT;
        int fz = TSLOT;
        #pragma unroll
        for (int i = TSLOT - 1; i >= 1; --i) fz = (t[i] == 0) ? i : fz;  // first zero
        shf[b] = fz;
        shs[b] = fz;
    }
    __syncthreads();
    for (int d = 1; d < 256; d <<= 1) {
        int v = (b >= d) ? shs[b - d] : 0;
        __syncthreads();
        shs[b] += v;
        __syncthreads();
    }
    const int nv = shs[255];
    const int npad = ((nv + TS - 1) / TS) * TS;

    if (blockIdx.x == 0) {
        if (b < 2) accum[b] = 0.0f;
        if (b == 2) *counter = 0;
        if (b == 3) { meta[0] = nv; meta[1] = npad; }
        if (b < npad - nv) clab[nv + b] = -1;  // <= TS-1 entries
    }

    // ---- per-wave row normalize (f32 -> unit-norm fp8 e4m3, compacted scatter) ----
    const int wv   = blockIdx.x * 4 + (threadIdx.x >> 6);
    const int lane = threadIdx.x & 63;
    const int bb = wv / TSLOT, tt = wv - bb * TSLOT;
    const int fzb = shf[bb];
    if (tt >= fzb) return;                      // wave-uniform: padded slot
    const int dest = (shs[bb] - fzb) + tt;      // exclusive prefix + slot

    const float* src = in + (size_t)wv * DIM + lane * 16;
    float4 v0 = *(const float4*)(src);
    float4 v1 = *(const float4*)(src + 4);
    float4 v2 = *(const float4*)(src + 8);
    float4 v3 = *(const float4*)(src + 12);
    float ss = v0.x*v0.x + v0.y*v0.y + v0.z*v0.z + v0.w*v0.w
             + v1.x*v1.x + v1.y*v1.y + v1.z*v1.z + v1.w*v1.w
             + v2.x*v2.x + v2.y*v2.y + v2.z*v2.z + v2.w*v2.w
             + v3.x*v3.x + v3.y*v3.y + v3.z*v3.z + v3.w*v3.w;
    #pragma unroll
    for (int off = 1; off < 64; off <<= 1) ss += __shfl_xor(ss, off);
    const float sc = 1.0f / fmaxf(sqrtf(ss), 1e-12f);
    float f[16] = {v0.x,v0.y,v0.z,v0.w, v1.x,v1.y,v1.z,v1.w,
                   v2.x,v2.y,v2.z,v2.w, v3.x,v3.y,v3.z,v3.w};
    uint4 o;
    unsigned int* ow = (unsigned int*)&o;
    #pragma unroll
    for (int q = 0; q < 4; ++q) {
        unsigned int u = 0;
        u = __builtin_amdgcn_cvt_pk_fp8_f32(f[q*4+0] * sc, f[q*4+1] * sc, u, 0);
        u = __builtin_amdgcn_cvt_pk_fp8_f32(f[q*4+2] * sc, f[q*4+3] * sc, u, 1);
        ow[q] = u;
    }
    *(uint4*)(cfb + (size_t)dest * DIM + lane * 16) = o;
    if (lane == 0) clab[dest] = tgt[wv * TSLOT / TSLOT == bb ? bb * TSLOT + tt : wv];  // = tgt[wv]
}

// ---------- symmetric fused GEMM: fp8, 192-tile, 8 waves, 4-buf depth-3 ----------
// Prefix-aware bijective XCD swizzle (computed from meta): XCD x gets a
// contiguous run of triangle indices -> A-panel L2 locality; balanced for
// any data-dependent active count.
__global__ __launch_bounds__(512) void gemm_kernel(const unsigned char* __restrict__ fb,
                                                   const int* __restrict__ clab,
                                                   const int* __restrict__ meta,
                                                   float* __restrict__ Ppos,
                                                   float* __restrict__ Pneg) {
    __shared__ __align__(16) char lds[4 * BUFSZ];  // 96 KB

    const int npad = meta[1];
    const int nstrips = npad / TS;
    const int nact = nstrips * (nstrips + 1) / 2;
    const int k = blockIdx.x >> 3, x = blockIdx.x & 7;
    const int q8 = nact >> 3, r8 = nact & 7;
    const int cnt = q8 + (x < r8 ? 1 : 0);
    if (k >= cnt) return;
    int t = x * q8 + (x < r8 ? x : r8) + k;
    int bi = 0;
    while (t >= nstrips - bi) { t -= nstrips - bi; ++bi; }
    const int bj = bi + t;
    const int row0 = bi * TS;
    const int col0 = bj * TS;
    const bool diag = (bi == bj);

    const int tid  = threadIdx.x;
    const int lane = tid & 63;
    const int w    = tid >> 6;         // 0..7
    const int wm   = w >> 2;           // row strip (96 rows)
    const int wn   = w & 3;            // col strip (48 cols)

    f32x4 acc[6][3] = {};
    const char* fbyte = (const char*)fb;

    auto stage = [&](int s) {
        char* buf = lds + (s & 3) * BUFSZ;
        const int k0b = s * 64;
        #pragma unroll
        for (int j = 0; j < 3; ++j) {
            const int c = w * 192 + j * 64 + lane;          // 0..1535
            const int cc = (c >= 768) ? c - 768 : c;
            const int base = (c >= 768) ? col0 : row0;
            const int r = cc >> 2, ks = cc & 3;
            const int srcoff = ((ks ^ ((r >> 1) & 3)) << 4);
            const char* g = fbyte + (size_t)(base + r) * DIM + k0b + srcoff;
            __builtin_amdgcn_global_load_lds(
                (const __attribute__((address_space(1))) void*)g,
                (__attribute__((address_space(3))) void*)(buf + c * 16),
                16, 0, 0);
        }
    };

    const int rsel = lane & 15, tsl = lane >> 4;
    auto compute = [&](int s) {
        const char* bA = lds + (s & 3) * BUFSZ;
        const char* bB = bA + 12288;
        l64x2 av[6], bv[3];
        #pragma unroll
        for (int m = 0; m < 6; ++m) {
            const int r = wm * 96 + m * 16 + rsel;
            av[m] = *(const l64x2*)(bA + r * 64 + ((tsl ^ ((r >> 1) & 3)) << 4));
        }
        #pragma unroll
        for (int n = 0; n < 3; ++n) {
            const int r = wn * 48 + n * 16 + rsel;
            bv[n] = *(const l64x2*)(bB + r * 64 + ((tsl ^ ((r >> 1) & 3)) << 4));
        }
        #pragma unroll
        for (int kk = 0; kk < 2; ++kk)
            #pragma unroll
            for (int m = 0; m < 6; ++m)
                #pragma unroll
                for (int n = 0; n < 3; ++n)
                    acc[m][n] = __builtin_amdgcn_mfma_f32_16x16x32_fp8_fp8(
                        av[m][kk], bv[n][kk], acc[m][n], 0, 0, 0);
    };

    stage(0); stage(1); stage(2);  // 9 loads/wave outstanding
    #pragma unroll 1
    for (int s = 0; s < KST - 3; ++s) {
        asm volatile("s_waitcnt vmcnt(6)" ::: "memory");
        __builtin_amdgcn_s_barrier();
        asm volatile("" ::: "memory");
        stage(s + 3);
        compute(s);
    }
    asm volatile("s_waitcnt vmcnt(6)" ::: "memory");
    __builtin_amdgcn_s_barrier();
    asm volatile("" ::: "memory");
    compute(KST - 3);
    asm volatile("s_waitcnt vmcnt(3)" ::: "memory");
    __builtin_amdgcn_s_barrier();
    asm volatile("" ::: "memory");
    compute(KST - 2);
    asm volatile("s_waitcnt vmcnt(0)" ::: "memory");
    __builtin_amdgcn_s_barrier();
    asm volatile("" ::: "memory");
    compute(KST - 1);

    // ---- epilogue: masked exp, cross-wave combine through LDS, coalesced stores ----
    const int c = rsel, g = tsl;
    float cpos[3] = {0, 0, 0}, cneg[3] = {0, 0, 0};
    float* fl = (float*)lds;  // buf0: last read by compute(12), all waves barriered since

    #pragma unroll
    for (int m = 0; m < 6; ++m) {
        #pragma unroll
        for (int rg = 0; rg < 4; ++rg) {
            const int gi = row0 + wm * 96 + m * 16 + g * 4 + rg;
            const int li = clab[gi];
            float rp = 0.0f, rn = 0.0f;
            #pragma unroll
            for (int n = 0; n < 3; ++n) {
                const int gj = col0 + wn * 48 + n * 16 + c;
                const int lj = clab[gj];
                const float s = acc[m][n][rg];
                if (li >= 0 && lj >= 0) {
                    if (li == lj) { float e = __expf(-s); rp += e; cpos[n] += e; }
                    else          { float e = __expf(s);  rn += e; cneg[n] += e; }
                }
            }
            #pragma unroll
            for (int off = 1; off <= 8; off <<= 1) {
                rp += __shfl_xor(rp, off);
                rn += __shfl_xor(rn, off);
            }
            if (c == 0) {
                int lr = m * 16 + g * 4 + rg;          // 0..95
                fl[w * 96 + lr]        = rp;           // [0, 768)
                fl[768 + w * 96 + lr]  = rn;           // [768, 1536)
            }
        }
    }
    #pragma unroll
    for (int n = 0; n < 3; ++n) {
        float p = cpos[n], q = cneg[n];
        p += __shfl_xor(p, 16); p += __shfl_xor(p, 32);
        q += __shfl_xor(q, 16); q += __shfl_xor(q, 32);
        if (g == 0) {
            int lc = n * 16 + c;                       // 0..47
            fl[1536 + w * 48 + lc] = p;                // [1536, 1920)
            fl[1920 + w * 48 + lc] = q;                // [1920, 2304)
        }
    }
    __syncthreads();
    if (tid < 192) {
        int sm = tid / 96, lr = tid % 96;
        float rp = 0.0f, rn = 0.0f;
        #pragma unroll
        for (int kk = 0; kk < 4; ++kk) {
            rp += fl[(sm * 4 + kk) * 96 + lr];
            rn += fl[768 + (sm * 4 + kk) * 96 + lr];
        }
        int gi = row0 + tid;
        Ppos[(size_t)bj * NTOT + gi] = rp;   // slot bj (>= bi), coalesced
        Pneg[(size_t)bj * NTOT + gi] = rn;
    } else if (tid < 384 && !diag) {
        int j = tid - 192, cn = j / 48, lc = j % 48;
        float p = fl[1536 + cn * 48 + lc] + fl[1536 + (4 + cn) * 48 + lc];
        float q = fl[1920 + cn * 48 + lc] + fl[1920 + (4 + cn) * 48 + lc];
        int gj = col0 + j;
        Ppos[(size_t)bi * NTOT + gj] = p;    // slot bi (< bj), coalesced
        Pneg[(size_t)bi * NTOT + gj] = q;
    }
}

// ---------- finalize: gather partials, masked mean, last block writes out ----------
__global__ __launch_bounds__(256) void finalize_kernel(const int* __restrict__ clab,
                                                       const int* __restrict__ meta,
                                                       const float* __restrict__ Ppos,
                                                       const float* __restrict__ Pneg,
                                                       float* __restrict__ accum,
                                                       int* __restrict__ counter,
                                                       float* __restrict__ out) {
    int i = blockIdx.x * blockDim.x + threadIdx.x;
    const int npad = meta[1];
    const int nta = npad / TS;
    float s = 0.0f, cnt = 0.0f;
    if (i < npad && clab[i] >= 0) {
        float sp = 0.0f, sn = 0.0f;
        for (int t = 0; t < nta; ++t) {
            sp += Ppos[(size_t)t * NTOT + i];
            sn += Pneg[(size_t)t * NTOT + i];
        }
        s = log1pf(sp * sn);
        cnt = 1.0f;
    }
    #pragma unroll
    for (int off = 1; off < 64; off <<= 1) {
        s   += __shfl_xor(s, off);
        cnt += __shfl_xor(cnt, off);
    }
    __shared__ float sh[8];
    int lane = threadIdx.x & 63, w = threadIdx.x >> 6;
    if (lane == 0) { sh[w] = s; sh[4 + w] = cnt; }
    __syncthreads();
    if (threadIdx.x == 0) {
        atomicAdd(&accum[0], sh[0] + sh[1] + sh[2] + sh[3]);
        atomicAdd(&accum[1], sh[4] + sh[5] + sh[6] + sh[7]);
        __threadfence();
        int done = atomicAdd(counter, 1);
        if (done == (int)gridDim.x - 1) {
            __threadfence();
            out[0] = accum[0] / accum[1];
        }
    }
}

extern "C" void kernel_launch(void* const* d_in, const int* in_sizes, int n_in,
                              void* d_out, int out_size, void* d_ws, size_t ws_size,
                              hipStream_t stream) {
    (void)in_sizes; (void)n_in; (void)out_size; (void)ws_size;
    const float* input_f = (const float*)d_in[0];
    const int*   target  = (const int*)d_in[1];
    float* out = (float*)d_out;

    char* ws = (char*)d_ws;
    const size_t FB_BYTES = (size_t)NTOT * DIM;          // 7,077,888 (fp8)
    unsigned char* cfb = (unsigned char*)ws;
    char* p = ws + FB_BYTES;
    int*   clab  = (int*)p;            p += NTOT * 4;
    int*   meta  = (int*)p;            p += 256;
    float* accum = (float*)p;          p += 128;
    int*   counter = (int*)p;          p += 128;
    float* Ppos  = (float*)p;          p += (size_t)NSMAX * NTOT * 4;  // 995 KB
    float* Pneg  = (float*)p;

    prep_norm_kernel<<<dim3(NTOT / 4), dim3(256), 0, stream>>>(input_f, target, cfb, clab, meta, accum, counter);
    gemm_kernel<<<dim3(NTRIMAX), dim3(512), 0, stream>>>(cfb, clab, meta, Ppos, Pneg);
    finalize_kernel<<<dim3((NTOT + 255) / 256), dim3(256), 0, stream>>>(clab, meta, Ppos, Pneg, accum, counter, out);
}